// Round 14
// baseline (27.964 us; speedup 1.0000x reference)
//
#include <hip/hip_runtime.h>

// GCNConv, full upper-tri graph + self loops, B=512, N=64, C=O=256.
// out[b,i,:] = relu( (1/sqrt(i+1)) * sum_{j<=i} (X[b]W)[j,:]/sqrt(j+1) + bias )
//
// R15: overlap via co-resident blocks, not intra-block scheduling.
// 512 blocks x 256 thr (4 waves), 1 graph/block, launch_bounds(256,2) ->
// <=256 VGPR enforced, 2 blocks/CU (LDS 64KB each). Block body is serial:
// DMA X (f32, global_load_lds, pre-swizzled source) -> vmcnt(0)+barrier ->
// gemm (A from LDS w/ in-loop bf16 cvt; B streamed per-kk from bf16 WT in
// L2 -- no W register file) -> scan -> store. One block's read stream runs
// while the sibling computes/stores; streams never interleave at issue time
// (R9/R13 lesson: interleaved reads stretch the critical stream).

#define BATCH 512
#define NNODE 64
#define CIN   256
#define COUT  256

typedef __bf16 bf16x8 __attribute__((ext_vector_type(8)));
typedef float  f32x4  __attribute__((ext_vector_type(4)));

__device__ __forceinline__ unsigned int f2bf_bits(float f) {
    unsigned int u = __builtin_bit_cast(unsigned int, f);
    return (u + 0x7fffu + ((u >> 16) & 1u)) >> 16;
}

// async global->LDS DMA, 16B per lane; LDS dest = wave-uniform base + lane*16
__device__ __forceinline__ void dma16(const float* g, float* l) {
    __builtin_amdgcn_global_load_lds(
        (const __attribute__((address_space(1))) unsigned int*)g,
        (__attribute__((address_space(3))) unsigned int*)l,
        16, 0, 0);
}

__global__ __launch_bounds__(256, 2) void gcn_fused(
    const float* __restrict__ X,
    const unsigned short* __restrict__ WT,   // bf16 bits, [COUT][CIN] (wprep)
    const float* __restrict__ bias,
    float* __restrict__ out)
{
    __shared__ float Xs[NNODE * CIN];        // 64 KB f32, source-swizzled
    const int tid  = threadIdx.x;
    const int lane = tid & 63;
    const int w    = tid >> 6;               // wave 0..3: cols [w*64, w*64+64)
    const int g    = lane >> 4;
    const int c    = lane & 15;
    const int b    = blockIdx.x;

    const float* xb = X + (size_t)b * (NNODE * CIN);

    // ---- 1) DMA the graph: wave w stages rows w*16 .. w*16+15.
    // Source element offset pre-swizzled (^ (row&7)<<2, 16B granule); LDS
    // written linearly -> Xs[row][e] = X[row][e ^ sw_row]. (R14-verified.) ----
    const int w16 = w * 16;
#pragma unroll
    for (int j = 0; j < 16; ++j) {
        int r = w16 + j;
        dma16(xb + r * 256 + ((lane * 4) ^ ((r & 7) << 2)), &Xs[r * 256]);
    }

    float bias_c[4];
#pragma unroll
    for (int nt = 0; nt < 4; ++nt)
        bias_c[nt] = bias[w * 64 + nt * 16 + c];

    float dd[4][4];                          // 1/sqrt(row+1) table
#pragma unroll
    for (int mt = 0; mt < 4; ++mt)
#pragma unroll
        for (int r = 0; r < 4; ++r)
            dd[mt][r] = rsqrtf((float)(mt * 16 + g * 4 + r + 1));

    // ---- 2) all DMAs (and bias) retired, then block-wide barrier ----
    asm volatile("s_waitcnt vmcnt(0)\n\ts_barrier" ::: "memory");
    __builtin_amdgcn_sched_barrier(0);

    // ---- 3) gemm: A from LDS (swizzled f32 reads + cvt), B from WT (L2) ----
    f32x4 acc[4][4] = {};                    // [mt][nt]
    const int sw = (c & 7) << 2;             // row&7 == c&7 (mt*16 % 8 == 0)
    const unsigned short* WTb = WT + (size_t)(w * 64 + c) * CIN + g * 8;
#pragma unroll
    for (int kk = 0; kk < 8; ++kk) {
        bf16x8 bf[4];
#pragma unroll
        for (int nt = 0; nt < 4; ++nt)
            // B[k=kk*32+g*8..+7][col=w*64+nt*16+c] == WT[col][k..k+7]; the 4
            // g-lanes of a c consume one 64B line fully -> 16 lines/instr.
            bf[nt] = *reinterpret_cast<const bf16x8*>(WTb + nt * 16 * CIN + kk * 32);
        bf16x8 a[4];
#pragma unroll
        for (int mt = 0; mt < 4; ++mt) {
            int row = mt * 16 + c;
            int x0  = kk * 32 + g * 8;
            f32x4 lo = *reinterpret_cast<const f32x4*>(&Xs[row * 256 + ((x0) ^ sw)]);
            f32x4 hi = *reinterpret_cast<const f32x4*>(&Xs[row * 256 + ((x0 + 4) ^ sw)]);
            bf16x8 t;
            t[0] = (__bf16)lo[0]; t[1] = (__bf16)lo[1];
            t[2] = (__bf16)lo[2]; t[3] = (__bf16)lo[3];
            t[4] = (__bf16)hi[0]; t[5] = (__bf16)hi[1];
            t[6] = (__bf16)hi[2]; t[7] = (__bf16)hi[3];
            a[mt] = t;
        }
#pragma unroll
        for (int mt = 0; mt < 4; ++mt)
#pragma unroll
            for (int nt = 0; nt < 4; ++nt)
                acc[mt][nt] = __builtin_amdgcn_mfma_f32_16x16x32_bf16(
                    a[mt], bf[nt], acc[mt][nt], 0, 0, 0);
    }

    // ---- 4) epilogue: row-scale, prefix over 64 rows, bias+relu, store ----
    float t_[4][4];
#pragma unroll
    for (int mt = 0; mt < 4; ++mt)
#pragma unroll
        for (int nt = 0; nt < 4; ++nt) {
            f32x4 v = acc[mt][nt];
            v[0] *= dd[mt][0]; v[1] *= dd[mt][1];
            v[2] *= dd[mt][2]; v[3] *= dd[mt][3];
            v[1] += v[0]; v[2] += v[1]; v[3] += v[2];
            acc[mt][nt] = v;
            t_[mt][nt] = v[3];
        }
    // xor-butterfly exclusive scan over the 4 g-groups, serial over mt
    float Ofs[4][4];                         // [mt][nt]
#pragma unroll
    for (int nt = 0; nt < 4; ++nt) {
        float run = 0.0f;
#pragma unroll
        for (int mt = 0; mt < 4; ++mt) {
            float v    = t_[mt][nt];
            float p    = __shfl_xor(v, 16, 64);
            float excl = (g & 1) ? p : 0.0f;
            float pair = v + p;
            float q    = __shfl_xor(pair, 32, 64);
            excl += (g & 2) ? q : 0.0f;
            Ofs[mt][nt] = run + excl;
            run += pair + q;
        }
    }

    float* ob = out + (size_t)b * (NNODE * COUT) + w * 64 + c;
#pragma unroll
    for (int mt = 0; mt < 4; ++mt)
#pragma unroll
        for (int r = 0; r < 4; ++r) {
            const int row = mt * 16 + g * 4 + r;
            const float dr = dd[mt][r];
#pragma unroll
            for (int nt = 0; nt < 4; ++nt) {
                float val = (acc[mt][nt][r] + Ofs[mt][nt]) * dr + bias_c[nt];
                ob[row * COUT + nt * 16] = fmaxf(val, 0.0f);
            }
        }
}

// W (f32, [K=256][N=256]) -> Wt (bf16 bits, [N=256][K=256])
__global__ void wprep(const float* __restrict__ W, unsigned short* __restrict__ Wt) {
    __shared__ unsigned short tile[64][72];
    const int tid = threadIdx.x;
    const int tk  = blockIdx.x & 3;
    const int tn  = blockIdx.x >> 2;
#pragma unroll
    for (int i = 0; i < 16; ++i) {
        int idx = tid + i * 256;
        int r  = idx >> 6;
        int cc = idx & 63;
        tile[cc][r] = (unsigned short)f2bf_bits(W[(tk * 64 + r) * 256 + tn * 64 + cc]);
    }
    __syncthreads();
#pragma unroll
    for (int i = 0; i < 16; ++i) {
        int idx = tid + i * 256;
        int rr = idx >> 6;
        int cc = idx & 63;
        Wt[(tn * 64 + rr) * 256 + tk * 64 + cc] = tile[rr][cc];
    }
}

extern "C" void kernel_launch(void* const* d_in, const int* in_sizes, int n_in,
                              void* d_out, int out_size, void* d_ws, size_t ws_size,
                              hipStream_t stream) {
    const float* x = (const float*)d_in[0];
    const float* W = (const float*)d_in[1];
    const float* bsp = (const float*)d_in[2];
    float* out = (float*)d_out;
    unsigned short* Wt = (unsigned short*)d_ws;

    hipLaunchKernelGGL(wprep, dim3(16), dim3(256), 0, stream, W, Wt);
    hipLaunchKernelGGL(gcn_fused, dim3(BATCH), dim3(256), 0, stream,
                       x, Wt, bsp, out);
}

// Round 15
// 25.432 us; speedup vs baseline: 1.0996x; 1.0996x over previous
//
#include <hip/hip_runtime.h>

// GCNConv, full upper-tri graph + self loops, B=512, N=64, C=O=256.
// out[b,i,:] = relu( (1/sqrt(i+1)) * sum_{j<=i} (X[b]W)[j,:]/sqrt(j+1) + bias )
//
// R16 = R8 byte-identical EXCEPT the W path: W is pre-transposed/converted to
// bf16 WT[N][K] by wprep, and each thread loads its fragments as 16 contiguous
// bf16x8 vector loads (same program position as R8's 128 scalar dwords).
// Fixes: vmcnt 6-bit ledger overflow (136 -> 24 outstanding), in-order-retire
// coupling of W waits to X loads, and halves W L2 traffic (64MB -> 32MB).

#define BATCH 512
#define NNODE 64
#define CIN   256
#define COUT  256

typedef __bf16 bf16x8 __attribute__((ext_vector_type(8)));
typedef float  f32x4  __attribute__((ext_vector_type(4)));

__device__ __forceinline__ unsigned int f2bf_bits(float f) {
    unsigned int u = __builtin_bit_cast(unsigned int, f);
    return (u + 0x7fffu + ((u >> 16) & 1u)) >> 16;
}

__global__ __launch_bounds__(512, 1) void gcn_fused(
    const float* __restrict__ X,
    const unsigned short* __restrict__ WT,   // bf16 bits, [COUT][CIN] (wprep)
    const float* __restrict__ bias,
    float* __restrict__ out)
{
    __shared__ uint4 Xs4[2][2048];           // [graph][32KB] swizzled bf16 X
    const int tid  = threadIdx.x;
    const int lane = tid & 63;
    const int w    = tid >> 6;               // wave 0..7: cols [w*32, w*32+32)
    const int g    = lane >> 4;
    const int c    = lane & 15;
    const int colbase = w * 32;
    const int xg   = blockIdx.x * 2;

    const float* xb0 = X + (size_t)xg * (NNODE * CIN);
    const float* xb1 = xb0 + NNODE * CIN;

    // ---- 1) issue g0 X loads first (the stream everything waits on) ----
    f32x4 pf[8];
#pragma unroll
    for (int i = 0; i < 4; ++i) {
        int ch  = tid + i * 512;             // 2048 chunks of 8 floats
        const f32x4* p = reinterpret_cast<const f32x4*>(
            xb0 + (ch >> 5) * CIN + ((ch & 31) << 3));
        pf[2 * i]     = p[0];
        pf[2 * i + 1] = p[1];
    }

    // ---- 2) W fragments: 16 contiguous bf16x8 loads (L2-resident WT) ----
    bf16x8 bfr[8][2];                        // 64 VGPR
    {
        const unsigned short* WTb = WT + (size_t)(colbase + c) * CIN + g * 8;
#pragma unroll
        for (int kk = 0; kk < 8; ++kk)
#pragma unroll
            for (int nt = 0; nt < 2; ++nt)
                bfr[kk][nt] = *reinterpret_cast<const bf16x8*>(WTb + nt * 16 * CIN + kk * 32);
    }
    float bias_c[2];
#pragma unroll
    for (int nt = 0; nt < 2; ++nt)
        bias_c[nt] = bias[colbase + nt * 16 + c];

    // ---- 3) convert g0 -> LDS buf0 (swizzled bf16) ----
#pragma unroll
    for (int i = 0; i < 4; ++i) {
        int ch  = tid + i * 512;
        int row = ch >> 5;
        int c8  = (ch & 31) << 3;
        f32x4 v0 = pf[2 * i], v1 = pf[2 * i + 1];
        bf16x8 h;
        h[0] = (__bf16)v0[0]; h[1] = (__bf16)v0[1];
        h[2] = (__bf16)v0[2]; h[3] = (__bf16)v0[3];
        h[4] = (__bf16)v1[0]; h[5] = (__bf16)v1[1];
        h[6] = (__bf16)v1[2]; h[7] = (__bf16)v1[3];
        int byte = (row << 9) + (c8 << 1);
        byte ^= (row & 7) << 4;
        *reinterpret_cast<uint4*>((unsigned char*)Xs4[0] + byte) =
            __builtin_bit_cast(uint4, h);
    }

    float dd[4][4];                          // 1/sqrt(row+1) table
#pragma unroll
    for (int mt = 0; mt < 4; ++mt)
#pragma unroll
        for (int r = 0; r < 4; ++r)
            dd[mt][r] = rsqrtf((float)(mt * 16 + g * 4 + r + 1));

    const int swz = (c & 7) << 4;

    auto gemm = [&](const unsigned char* Xs, f32x4 (&acc)[4][2]) {
#pragma unroll
        for (int kk = 0; kk < 8; ++kk) {
            bf16x8 a[4];
#pragma unroll
            for (int mt = 0; mt < 4; ++mt) {
                int byte = ((mt * 16 + c) << 9) + (kk << 6) + (g << 4);
                byte ^= swz;
                a[mt] = *reinterpret_cast<const bf16x8*>(Xs + byte);
            }
#pragma unroll
            for (int mt = 0; mt < 4; ++mt)
#pragma unroll
                for (int nt = 0; nt < 2; ++nt)
                    acc[mt][nt] = __builtin_amdgcn_mfma_f32_16x16x32_bf16(
                        a[mt], bfr[kk][nt], acc[mt][nt], 0, 0, 0);
        }
    };

    auto epilogue = [&](f32x4 (&acc)[4][2], float* ob) {
        float t_[4][2];
#pragma unroll
        for (int mt = 0; mt < 4; ++mt)
#pragma unroll
            for (int nt = 0; nt < 2; ++nt) {
                f32x4 v = acc[mt][nt];
                v[0] *= dd[mt][0]; v[1] *= dd[mt][1];
                v[2] *= dd[mt][2]; v[3] *= dd[mt][3];
                v[1] += v[0]; v[2] += v[1]; v[3] += v[2];
                acc[mt][nt] = v;
                t_[mt][nt] = v[3];
            }
        float Ofs[4][2];
#pragma unroll
        for (int nt = 0; nt < 2; ++nt) {
            float run = 0.0f;
#pragma unroll
            for (int mt = 0; mt < 4; ++mt) {
                float v    = t_[mt][nt];
                float p    = __shfl_xor(v, 16, 64);
                float excl = (g & 1) ? p : 0.0f;
                float pair = v + p;
                float q    = __shfl_xor(pair, 32, 64);
                excl += (g & 2) ? q : 0.0f;
                Ofs[mt][nt] = run + excl;
                run += pair + q;
            }
        }
#pragma unroll
        for (int mt = 0; mt < 4; ++mt)
#pragma unroll
            for (int r = 0; r < 4; ++r) {
                const int row = mt * 16 + g * 4 + r;
                const float dr = dd[mt][r];
#pragma unroll
                for (int nt = 0; nt < 2; ++nt) {
                    float val = (acc[mt][nt][r] + Ofs[mt][nt]) * dr + bias_c[nt];
                    ob[row * COUT + nt * 16] = fmaxf(val, 0.0f);
                }
            }
    };

    // barrier BEFORE issuing g1 loads (R8 discipline: nothing outstanding)
    __syncthreads();

    // ---- issue g1 X loads: they fly under g0's compute + stores ----
    f32x4 pg[8];
#pragma unroll
    for (int i = 0; i < 4; ++i) {
        int ch  = tid + i * 512;
        const f32x4* p = reinterpret_cast<const f32x4*>(
            xb1 + (ch >> 5) * CIN + ((ch & 31) << 3));
        pg[2 * i]     = p[0];
        pg[2 * i + 1] = p[1];
    }

    f32x4 acc0[4][2] = {};
    gemm((const unsigned char*)Xs4[0], acc0);

    // ---- convert g1 -> LDS buf1 (wave-local vmcnt wait, not a block drain) ----
#pragma unroll
    for (int i = 0; i < 4; ++i) {
        int ch  = tid + i * 512;
        int row = ch >> 5;
        int c8  = (ch & 31) << 3;
        f32x4 v0 = pg[2 * i], v1 = pg[2 * i + 1];
        bf16x8 h;
        h[0] = (__bf16)v0[0]; h[1] = (__bf16)v0[1];
        h[2] = (__bf16)v0[2]; h[3] = (__bf16)v0[3];
        h[4] = (__bf16)v1[0]; h[5] = (__bf16)v1[1];
        h[6] = (__bf16)v1[2]; h[7] = (__bf16)v1[3];
        int byte = (row << 9) + (c8 << 1);
        byte ^= (row & 7) << 4;
        *reinterpret_cast<uint4*>((unsigned char*)Xs4[1] + byte) =
            __builtin_bit_cast(uint4, h);
    }

    // ---- g0 epilogue ----
    epilogue(acc0, out + (size_t)xg * (NNODE * COUT) + colbase + c);

    __syncthreads();

    f32x4 acc1[4][2] = {};
    gemm((const unsigned char*)Xs4[1], acc1);
    epilogue(acc1, out + (size_t)(xg + 1) * (NNODE * COUT) + colbase + c);
}

// W (f32, [K=256][N=256]) -> Wt (bf16 bits, [N=256][K=256])
__global__ void wprep(const float* __restrict__ W, unsigned short* __restrict__ Wt) {
    __shared__ unsigned short tile[64][72];
    const int tid = threadIdx.x;
    const int tk  = blockIdx.x & 3;
    const int tn  = blockIdx.x >> 2;
#pragma unroll
    for (int i = 0; i < 16; ++i) {
        int idx = tid + i * 256;
        int r  = idx >> 6;
        int cc = idx & 63;
        tile[cc][r] = (unsigned short)f2bf_bits(W[(tk * 64 + r) * 256 + tn * 64 + cc]);
    }
    __syncthreads();
#pragma unroll
    for (int i = 0; i < 16; ++i) {
        int idx = tid + i * 256;
        int rr = idx >> 6;
        int cc = idx & 63;
        Wt[(tn * 64 + rr) * 256 + tk * 64 + cc] = tile[rr][cc];
    }
}

extern "C" void kernel_launch(void* const* d_in, const int* in_sizes, int n_in,
                              void* d_out, int out_size, void* d_ws, size_t ws_size,
                              hipStream_t stream) {
    const float* x = (const float*)d_in[0];
    const float* W = (const float*)d_in[1];
    const float* bsp = (const float*)d_in[2];
    float* out = (float*)d_out;
    unsigned short* Wt = (unsigned short*)d_ws;

    hipLaunchKernelGGL(wprep, dim3(16), dim3(256), 0, stream, W, Wt);
    hipLaunchKernelGGL(gcn_fused, dim3(BATCH / 2), dim3(512), 0, stream,
                       x, Wt, bsp, out);
}